// Round 1
// baseline (2804.328 us; speedup 1.0000x reference)
//
#include <hip/hip_runtime.h>

// Problem constants (match reference)
#define T_STEPS 2048
#define BBATCH  64
#define S_DIM   256
#define IN_DIM  64
#define DIST_DIM 32

// Chunked-scan configuration
#define P_CHUNKS 64
#define L_CHUNK  32            // T_STEPS / P_CHUNKS
#define BG       4             // batch groups per chunk
#define B_PER    (BBATCH / BG) // 16 batch rows per block

// ---------------------------------------------------------------------------
// Kernel 1: drive[t,b,s] = sum_i U[t,b,i]*Bw[s,i] + sum_d D[t,b,d]*Ew[s,d]
// One block per t. Thread j = state index s. Weights rows held in registers,
// U_t/D_t staged in LDS and read as broadcast float4.
// ---------------------------------------------------------------------------
__global__ __launch_bounds__(256) void k_drive(const float* __restrict__ U,
                                               const float* __restrict__ D,
                                               const float* __restrict__ Bw,
                                               const float* __restrict__ Ew,
                                               float* __restrict__ drive) {
    __shared__ float Us[BBATCH][IN_DIM];    // 16 KB
    __shared__ float Ds[BBATCH][DIST_DIM];  // 8 KB
    const int t = blockIdx.x;
    const int j = threadIdx.x;  // s index

    const float* Ut = U + (size_t)t * BBATCH * IN_DIM;
    for (int idx = j; idx < BBATCH * IN_DIM; idx += 256) ((float*)Us)[idx] = Ut[idx];
    const float* Dt = D + (size_t)t * BBATCH * DIST_DIM;
    for (int idx = j; idx < BBATCH * DIST_DIM; idx += 256) ((float*)Ds)[idx] = Dt[idx];

    // Load my weight rows into registers (96 floats)
    float bw[IN_DIM];
    float ew[DIST_DIM];
    const float4* bwp = (const float4*)(Bw + (size_t)j * IN_DIM);
#pragma unroll
    for (int q = 0; q < IN_DIM / 4; q++) {
        float4 v = bwp[q];
        bw[4 * q + 0] = v.x; bw[4 * q + 1] = v.y; bw[4 * q + 2] = v.z; bw[4 * q + 3] = v.w;
    }
    const float4* ewp = (const float4*)(Ew + (size_t)j * DIST_DIM);
#pragma unroll
    for (int q = 0; q < DIST_DIM / 4; q++) {
        float4 v = ewp[q];
        ew[4 * q + 0] = v.x; ew[4 * q + 1] = v.y; ew[4 * q + 2] = v.z; ew[4 * q + 3] = v.w;
    }
    __syncthreads();

    float* out = drive + (size_t)t * BBATCH * S_DIM;
    for (int b = 0; b < BBATCH; b++) {
        float acc = 0.f;
#pragma unroll
        for (int q = 0; q < IN_DIM / 4; q++) {
            float4 u = *(const float4*)(&Us[b][4 * q]);
            acc += u.x * bw[4 * q] + u.y * bw[4 * q + 1] + u.z * bw[4 * q + 2] + u.w * bw[4 * q + 3];
        }
#pragma unroll
        for (int q = 0; q < DIST_DIM / 4; q++) {
            float4 d4 = *(const float4*)(&Ds[b][4 * q]);
            acc += d4.x * ew[4 * q] + d4.y * ew[4 * q + 1] + d4.z * ew[4 * q + 2] + d4.w * ew[4 * q + 3];
        }
        out[(size_t)b * S_DIM + j] = acc;
    }
}

// ---------------------------------------------------------------------------
// Kernel 2: Out = In * In  (256x256 matrix square, for M = A^32 via 5 launches)
// Block r computes row r of Out.
// ---------------------------------------------------------------------------
__global__ __launch_bounds__(256) void k_matsq(const float* __restrict__ In,
                                               float* __restrict__ Out) {
    const int r = blockIdx.x;
    const int j = threadIdx.x;
    __shared__ float row[S_DIM];
    row[j] = In[(size_t)r * S_DIM + j];
    __syncthreads();
    float acc = 0.f;
#pragma unroll 4
    for (int k = 0; k < S_DIM; k++) {
        acc += row[k] * In[(size_t)k * S_DIM + j];
    }
    Out[(size_t)r * S_DIM + j] = acc;
}

// ---------------------------------------------------------------------------
// Kernel 3 (phase 1): per (chunk p, batch-group bg), local scan with zero init:
//   l = A*l + drive[t], t in [p*L, p*L+L). Writes final l into F[p][b][s].
// Thread j owns state element s=j for all 16 batch rows of the group.
// A row j streamed from L2 (float4); state in LDS, broadcast float4 reads.
// ---------------------------------------------------------------------------
__global__ __launch_bounds__(256) void k_phase1(const float* __restrict__ A,
                                                const float* __restrict__ drive,
                                                float* __restrict__ F) {
    __shared__ float Xs[B_PER][S_DIM];  // 16 KB
    const int p = blockIdx.x;
    const int bg = blockIdx.y;
    const int b0 = bg * B_PER;
    const int j = threadIdx.x;

#pragma unroll
    for (int bb = 0; bb < B_PER; bb++) Xs[bb][j] = 0.f;
    __syncthreads();

    const float4* Arow = (const float4*)(A + (size_t)j * S_DIM);

    for (int step = 0; step < L_CHUNK; step++) {
        const int t = p * L_CHUNK + step;
        const float* drv = drive + ((size_t)t * BBATCH + b0) * S_DIM;
        float acc[B_PER];
#pragma unroll
        for (int bb = 0; bb < B_PER; bb++) acc[bb] = drv[(size_t)bb * S_DIM + j];

#pragma unroll 4
        for (int kq = 0; kq < S_DIM / 4; kq++) {
            float4 a = Arow[kq];
#pragma unroll
            for (int bb = 0; bb < B_PER; bb++) {
                float4 xv = *(const float4*)(&Xs[bb][kq * 4]);
                acc[bb] += a.x * xv.x + a.y * xv.y + a.z * xv.z + a.w * xv.w;
            }
        }
        __syncthreads();  // everyone done reading old state
#pragma unroll
        for (int bb = 0; bb < B_PER; bb++) Xs[bb][j] = acc[bb];
        __syncthreads();  // new state visible
    }

    float* Fp = F + ((size_t)p * BBATCH + b0) * S_DIM;
#pragma unroll
    for (int bb = 0; bb < B_PER; bb++) Fp[(size_t)bb * S_DIM + j] = Xs[bb][j];
}

// ---------------------------------------------------------------------------
// Kernel 4 (phase 2): serial chunk combine, independent per batch row b:
//   C[0] = x0;  C[p] = M*C[p-1] + F[p-1]
// One block per b (64 blocks), state c in LDS, M rows streamed from L2.
// ---------------------------------------------------------------------------
__global__ __launch_bounds__(256) void k_phase2(const float* __restrict__ M,
                                                const float* __restrict__ F,
                                                const float* __restrict__ x0,
                                                float* __restrict__ C) {
    __shared__ float c[S_DIM];
    const int b = blockIdx.x;
    const int j = threadIdx.x;

    float cj = x0[(size_t)b * S_DIM + j];
    C[(size_t)b * S_DIM + j] = cj;  // C[p=0]
    c[j] = cj;
    __syncthreads();

    const float4* Mrow = (const float4*)(M + (size_t)j * S_DIM);
    for (int p = 1; p < P_CHUNKS; p++) {
        float acc = F[(((size_t)(p - 1)) * BBATCH + b) * S_DIM + j];
#pragma unroll 4
        for (int kq = 0; kq < S_DIM / 4; kq++) {
            float4 m = Mrow[kq];
            float4 cv = *(const float4*)(&c[kq * 4]);
            acc += m.x * cv.x + m.y * cv.y + m.z * cv.z + m.w * cv.w;
        }
        __syncthreads();
        c[j] = acc;
        __syncthreads();
        C[((size_t)p * BBATCH + b) * S_DIM + j] = acc;
    }
}

// ---------------------------------------------------------------------------
// Kernel 5 (phase 3): re-run in-chunk scan from true start state C[p], writing
// X[t] to both output copies. out1 currently holds drive[t] (read before
// overwrite, chunk-private slots -> safe).
// ---------------------------------------------------------------------------
__global__ __launch_bounds__(256) void k_phase3(const float* __restrict__ A,
                                                const float* __restrict__ C,
                                                float* __restrict__ out1,
                                                float* __restrict__ out2) {
    __shared__ float Xs[B_PER][S_DIM];
    const int p = blockIdx.x;
    const int bg = blockIdx.y;
    const int b0 = bg * B_PER;
    const int j = threadIdx.x;

#pragma unroll
    for (int bb = 0; bb < B_PER; bb++)
        Xs[bb][j] = C[((size_t)p * BBATCH + b0 + bb) * S_DIM + j];
    __syncthreads();

    const float4* Arow = (const float4*)(A + (size_t)j * S_DIM);

    for (int step = 0; step < L_CHUNK; step++) {
        const size_t t = (size_t)p * L_CHUNK + step;
        float* o1 = out1 + (t * BBATCH + b0) * S_DIM;
        float* o2 = out2 + (t * BBATCH + b0) * S_DIM;
        float acc[B_PER];
#pragma unroll
        for (int bb = 0; bb < B_PER; bb++) acc[bb] = o1[(size_t)bb * S_DIM + j];  // drive

#pragma unroll 4
        for (int kq = 0; kq < S_DIM / 4; kq++) {
            float4 a = Arow[kq];
#pragma unroll
            for (int bb = 0; bb < B_PER; bb++) {
                float4 xv = *(const float4*)(&Xs[bb][kq * 4]);
                acc[bb] += a.x * xv.x + a.y * xv.y + a.z * xv.z + a.w * xv.w;
            }
        }
        __syncthreads();
#pragma unroll
        for (int bb = 0; bb < B_PER; bb++) {
            Xs[bb][j] = acc[bb];
            o1[(size_t)bb * S_DIM + j] = acc[bb];
            o2[(size_t)bb * S_DIM + j] = acc[bb];
        }
        __syncthreads();
    }
}

// ---------------------------------------------------------------------------
extern "C" void kernel_launch(void* const* d_in, const int* in_sizes, int n_in,
                              void* d_out, int out_size, void* d_ws, size_t ws_size,
                              hipStream_t stream) {
    const float* x  = (const float*)d_in[0];  // (B, S)
    const float* U  = (const float*)d_in[1];  // (T, B, IN)
    const float* D  = (const float*)d_in[2];  // (T, B, DIST)
    const float* Aw = (const float*)d_in[3];  // (S, S)
    const float* Bw = (const float*)d_in[4];  // (S, IN)
    const float* Ew = (const float*)d_in[5];  // (S, DIST)

    float* out  = (float*)d_out;
    float* out1 = out;                                        // X copy 1 (also drive scratch)
    float* out2 = out + (size_t)T_STEPS * BBATCH * S_DIM;     // X copy 2

    // Workspace layout (floats): F (P*B*S), C (P*B*S), M ping/pong (2 * S*S)
    float* F  = (float*)d_ws;
    float* C  = F + (size_t)P_CHUNKS * BBATCH * S_DIM;
    float* M1 = C + (size_t)P_CHUNKS * BBATCH * S_DIM;
    float* M2 = M1 + (size_t)S_DIM * S_DIM;

    // 1) drive -> out1
    k_drive<<<T_STEPS, 256, 0, stream>>>(U, D, Bw, Ew, out1);

    // 2) M = A^32 by repeated squaring (A^2 -> A^4 -> A^8 -> A^16 -> A^32)
    k_matsq<<<S_DIM, 256, 0, stream>>>(Aw, M1);
    k_matsq<<<S_DIM, 256, 0, stream>>>(M1, M2);
    k_matsq<<<S_DIM, 256, 0, stream>>>(M2, M1);
    k_matsq<<<S_DIM, 256, 0, stream>>>(M1, M2);
    k_matsq<<<S_DIM, 256, 0, stream>>>(M2, M1);  // M1 = A^32

    // 3) chunk-local scans (zero init) -> F
    k_phase1<<<dim3(P_CHUNKS, BG), 256, 0, stream>>>(Aw, out1, F);

    // 4) serial chunk combine -> C (chunk start states)
    k_phase2<<<BBATCH, 256, 0, stream>>>(M1, F, x, C);

    // 5) final scan with true start states, write X to both output copies
    k_phase3<<<dim3(P_CHUNKS, BG), 256, 0, stream>>>(Aw, C, out1, out2);
}

// Round 2
// 1339.857 us; speedup vs baseline: 2.0930x; 2.0930x over previous
//
#include <hip/hip_runtime.h>

#define T_STEPS 2048
#define BBATCH  64
#define S_DIM   256
#define IN_DIM  64
#define DIST_DIM 32

// Chunked scan: P chunks of L steps; per-block batch group of 16.
#define P_CHUNKS 64
#define L_CHUNK  32
#define BG       4
#define B_PER    16
// Phase-2 two-level combine: NG groups of G chunks.
#define NGRP 8
#define GSZ  8

typedef __attribute__((ext_vector_type(8))) short short8;
typedef __attribute__((ext_vector_type(4))) float float4v;

// ---- bf16 helpers (RNE) ---------------------------------------------------
static __device__ __forceinline__ short f2bf(float f) {
    unsigned u = __builtin_bit_cast(unsigned, f);
    u += 0x7FFF + ((u >> 16) & 1);          // round-to-nearest-even
    return (short)(u >> 16);
}
static __device__ __forceinline__ float bf2f(short s) {
    unsigned u = ((unsigned)(unsigned short)s) << 16;
    return __builtin_bit_cast(float, u);
}
static __device__ __forceinline__ void split3(float x, short& h, short& m, short& l) {
    h = f2bf(x);
    float r = x - bf2f(h);
    m = f2bf(r);
    l = f2bf(r - bf2f(m));
}

// ---------------------------------------------------------------------------
// k_splitA: A (fp32 [256][256]) -> Ah/Am/Al bf16 splits (row-major [s][k]).
// ---------------------------------------------------------------------------
__global__ __launch_bounds__(256) void k_splitA(const float* __restrict__ A,
                                                short* __restrict__ Ah,
                                                short* __restrict__ Am,
                                                short* __restrict__ Al) {
    int idx = (blockIdx.x * 256 + threadIdx.x) * 4;
    float4v a = *(const float4v*)(A + idx);
#pragma unroll
    for (int e = 0; e < 4; e++) {
        short h, m, l;
        split3(a[e], h, m, l);
        Ah[idx + e] = h; Am[idx + e] = m; Al[idx + e] = l;
    }
}

// ---------------------------------------------------------------------------
// k_drive: drive[t,b,s] = U[t,b,:]·Bw[s,:] + D[t,b,:]·Ew[s,:]
// U/D addresses are wave-uniform -> compiler scalarizes to s_load (free
// broadcast via SGPR), weights live in VGPRs. grid (T, 4): 16 b per block.
// ---------------------------------------------------------------------------
__global__ __launch_bounds__(256) void k_drive(const float* __restrict__ U,
                                               const float* __restrict__ D,
                                               const float* __restrict__ Bw,
                                               const float* __restrict__ Ew,
                                               float* __restrict__ drive) {
    const int t  = blockIdx.x;
    const int b0 = blockIdx.y * 16;
    const int j  = threadIdx.x;

    float bw[IN_DIM], ew[DIST_DIM];
    const float4v* bwp = (const float4v*)(Bw + (size_t)j * IN_DIM);
#pragma unroll
    for (int q = 0; q < IN_DIM / 4; q++) {
        float4v v = bwp[q];
        bw[4*q] = v[0]; bw[4*q+1] = v[1]; bw[4*q+2] = v[2]; bw[4*q+3] = v[3];
    }
    const float4v* ewp = (const float4v*)(Ew + (size_t)j * DIST_DIM);
#pragma unroll
    for (int q = 0; q < DIST_DIM / 4; q++) {
        float4v v = ewp[q];
        ew[4*q] = v[0]; ew[4*q+1] = v[1]; ew[4*q+2] = v[2]; ew[4*q+3] = v[3];
    }

    const float* Ut = U + ((size_t)t * BBATCH + b0) * IN_DIM;
    const float* Dt = D + ((size_t)t * BBATCH + b0) * DIST_DIM;
    float* outp = drive + ((size_t)t * BBATCH + b0) * S_DIM + j;

    for (int bb = 0; bb < 16; bb++) {
        float acc = 0.f;
#pragma unroll
        for (int k = 0; k < IN_DIM; k++) acc += Ut[bb * IN_DIM + k] * bw[k];
#pragma unroll
        for (int k = 0; k < DIST_DIM; k++) acc += Dt[bb * DIST_DIM + k] * ew[k];
        outp[(size_t)bb * S_DIM] = acc;
    }
}

// ---------------------------------------------------------------------------
// k_matsq: Out = In*In (256x256) — for A^2..A^256 powers.
// ---------------------------------------------------------------------------
__global__ __launch_bounds__(256) void k_matsq(const float* __restrict__ In,
                                               float* __restrict__ Out) {
    const int r = blockIdx.x;
    const int j = threadIdx.x;
    __shared__ float row[S_DIM];
    row[j] = In[(size_t)r * S_DIM + j];
    __syncthreads();
    float acc = 0.f;
#pragma unroll 4
    for (int k = 0; k < S_DIM; k++) acc += row[k] * In[(size_t)k * S_DIM + j];
    Out[(size_t)r * S_DIM + j] = acc;
}

// ---------------------------------------------------------------------------
// k_scan<PHASE3>: the MFMA chunk scanner.
//   Per block: chunk p, batch rows [b0, b0+16). 512 threads = 8 waves.
//   Wave w holds A_w bf16-split B-fragments for n in [32w, 32w+32) in
//   REGISTERS (2 ntiles x 8 ktiles x 3 splits x short8 = 192 VGPR).
//   State fragments (Xh/Xm/Xl, A-operand layout, lane-linear) in LDS.
//   Step: 96 MFMA (6-product split) -> D + drive -> Xf (fp32) ->
//         rebuild frags + (phase3) coalesced output stores.
// PHASE3=false: start from zero, write final state to Fout.
// PHASE3=true : start from Cin[p], write X to out1 & out2 each step
//               (out1 slot t holds drive[t], read before overwrite).
// ---------------------------------------------------------------------------
template <bool PHASE3>
__global__ __launch_bounds__(512, 2) void k_scan(const short* __restrict__ Ah,
                                                 const short* __restrict__ Am,
                                                 const short* __restrict__ Al,
                                                 const float* __restrict__ drive,
                                                 const float* __restrict__ Cin,
                                                 float* __restrict__ Fout,
                                                 float* __restrict__ out1,
                                                 float* __restrict__ out2) {
    __shared__ float Xf[16][260];     // fp32 state, pitch 260 for bank spread
    __shared__ short Xh[8][512];      // [ktile][lane*8+j] lane-linear frags
    __shared__ short Xm[8][512];
    __shared__ short Xl[8][512];

    const int p    = blockIdx.x;
    const int b0   = blockIdx.y * B_PER;
    const int tid  = threadIdx.x;
    const int lane = tid & 63;
    const int wave = tid >> 6;     // 0..7
    const int r16  = lane & 15;
    const int q    = lane >> 4;    // 0..3

    // ---- preload A_w fragments (registers, persistent across all steps)
    short8 BhF[2][8], BmF[2][8], BlF[2][8];
#pragma unroll
    for (int nt = 0; nt < 2; nt++) {
        const int row = wave * 32 + nt * 16 + r16;
#pragma unroll
        for (int kt = 0; kt < 8; kt++) {
            const int off = row * 256 + kt * 32 + q * 8;
            BhF[nt][kt] = *(const short8*)(Ah + off);
            BmF[nt][kt] = *(const short8*)(Am + off);
            BlF[nt][kt] = *(const short8*)(Al + off);
        }
    }

    // ---- initial state fragments
    {
        const int kt = tid >> 6, sl = tid & 63;
        const int qs = sl >> 4, bs = sl & 15;
        const int k0 = kt * 32 + qs * 8;
        if (PHASE3) {
            const float* src = Cin + (((size_t)p * BBATCH) + b0 + bs) * S_DIM + k0;
            float4v v0 = *(const float4v*)(src);
            float4v v1 = *(const float4v*)(src + 4);
            short hh[8], mm[8], ll[8];
#pragma unroll
            for (int e = 0; e < 4; e++) split3(v0[e], hh[e], mm[e], ll[e]);
#pragma unroll
            for (int e = 0; e < 4; e++) split3(v1[e], hh[4+e], mm[4+e], ll[4+e]);
            short8 sh, sm, sv;
#pragma unroll
            for (int e = 0; e < 8; e++) { sh[e] = hh[e]; sm[e] = mm[e]; sv[e] = ll[e]; }
            *(short8*)&Xh[kt][sl * 8] = sh;
            *(short8*)&Xm[kt][sl * 8] = sm;
            *(short8*)&Xl[kt][sl * 8] = sv;
        } else {
            float4v z = {0.f, 0.f, 0.f, 0.f};
            *(float4v*)&Xh[kt][sl * 8] = z;
            *(float4v*)&Xm[kt][sl * 8] = z;
            *(float4v*)&Xl[kt][sl * 8] = z;
        }
    }
    __syncthreads();

    for (int step = 0; step < L_CHUNK; step++) {
        const int t = p * L_CHUNK + step;

        // ---- MFMA pass: D = A·x  (6-product bf16x3 split, smallest first)
        float4v acc0 = {0.f, 0.f, 0.f, 0.f};
        float4v acc1 = {0.f, 0.f, 0.f, 0.f};
#pragma unroll
        for (int kt = 0; kt < 8; kt++) {
            short8 xh = *(const short8*)&Xh[kt][lane * 8];
            short8 xm = *(const short8*)&Xm[kt][lane * 8];
            short8 xl = *(const short8*)&Xl[kt][lane * 8];
            acc0 = __builtin_amdgcn_mfma_f32_16x16x32_bf16(xl, BhF[0][kt], acc0, 0, 0, 0);
            acc0 = __builtin_amdgcn_mfma_f32_16x16x32_bf16(xm, BmF[0][kt], acc0, 0, 0, 0);
            acc0 = __builtin_amdgcn_mfma_f32_16x16x32_bf16(xh, BlF[0][kt], acc0, 0, 0, 0);
            acc0 = __builtin_amdgcn_mfma_f32_16x16x32_bf16(xm, BhF[0][kt], acc0, 0, 0, 0);
            acc0 = __builtin_amdgcn_mfma_f32_16x16x32_bf16(xh, BmF[0][kt], acc0, 0, 0, 0);
            acc0 = __builtin_amdgcn_mfma_f32_16x16x32_bf16(xh, BhF[0][kt], acc0, 0, 0, 0);
            acc1 = __builtin_amdgcn_mfma_f32_16x16x32_bf16(xl, BhF[1][kt], acc1, 0, 0, 0);
            acc1 = __builtin_amdgcn_mfma_f32_16x16x32_bf16(xm, BmF[1][kt], acc1, 0, 0, 0);
            acc1 = __builtin_amdgcn_mfma_f32_16x16x32_bf16(xh, BlF[1][kt], acc1, 0, 0, 0);
            acc1 = __builtin_amdgcn_mfma_f32_16x16x32_bf16(xm, BhF[1][kt], acc1, 0, 0, 0);
            acc1 = __builtin_amdgcn_mfma_f32_16x16x32_bf16(xh, BmF[1][kt], acc1, 0, 0, 0);
            acc1 = __builtin_amdgcn_mfma_f32_16x16x32_bf16(xh, BhF[1][kt], acc1, 0, 0, 0);
        }

        // ---- add drive, write new state (fp32) to Xf in D-layout
        {
            const float* drvp = drive + ((size_t)t * BBATCH + b0) * S_DIM;
            const int col0 = wave * 32 + r16;
#pragma unroll
            for (int r = 0; r < 4; r++) {
                const int brow = q * 4 + r;
                Xf[brow][col0]      = acc0[r] + drvp[brow * S_DIM + col0];
                Xf[brow][col0 + 16] = acc1[r] + drvp[brow * S_DIM + col0 + 16];
            }
        }
        __syncthreads();

        // ---- rebuild bf16 split fragments from Xf
        {
            const int kt = tid >> 6, sl = tid & 63;
            const int qs = sl >> 4, bs = sl & 15;
            const int k0 = kt * 32 + qs * 8;
            float4v v0 = *(const float4v*)&Xf[bs][k0];
            float4v v1 = *(const float4v*)&Xf[bs][k0 + 4];
            short hh[8], mm[8], ll[8];
#pragma unroll
            for (int e = 0; e < 4; e++) split3(v0[e], hh[e], mm[e], ll[e]);
#pragma unroll
            for (int e = 0; e < 4; e++) split3(v1[e], hh[4+e], mm[4+e], ll[4+e]);
            short8 sh, sm, sv;
#pragma unroll
            for (int e = 0; e < 8; e++) { sh[e] = hh[e]; sm[e] = mm[e]; sv[e] = ll[e]; }
            *(short8*)&Xh[kt][sl * 8] = sh;
            *(short8*)&Xm[kt][sl * 8] = sm;
            *(short8*)&Xl[kt][sl * 8] = sv;
        }

        // ---- outputs (coalesced float4 from Xf)
        if (PHASE3) {
            const int c4 = (tid & 63) * 4, bg2 = tid >> 6;
            const size_t base = (size_t)t * BBATCH + b0;
#pragma unroll
            for (int h = 0; h < 2; h++) {
                const int brow = bg2 + h * 8;
                float4v v = *(const float4v*)&Xf[brow][c4];
                *(float4v*)(out1 + (base + brow) * S_DIM + c4) = v;
                *(float4v*)(out2 + (base + brow) * S_DIM + c4) = v;
            }
        } else if (step == L_CHUNK - 1) {
            const int c4 = (tid & 63) * 4, bg2 = tid >> 6;
#pragma unroll
            for (int h = 0; h < 2; h++) {
                const int brow = bg2 + h * 8;
                float4v v = *(const float4v*)&Xf[brow][c4];
                *(float4v*)(Fout + (((size_t)p * BBATCH) + b0 + brow) * S_DIM + c4) = v;
            }
        }
        __syncthreads();
    }
}

// ---------------------------------------------------------------------------
// Phase-2 combine kernels (fp32, small). F[p][b][s] with p = g*GSZ + i.
// ---------------------------------------------------------------------------
__global__ __launch_bounds__(256) void k_comb_zero(const float* __restrict__ M,
                                                   const float* __restrict__ F,
                                                   float* __restrict__ Sg) {
    const int g = blockIdx.x, b = blockIdx.y, j = threadIdx.x;
    __shared__ float c[2][S_DIM];
    c[0][j] = F[(((size_t)g * GSZ) * BBATCH + b) * S_DIM + j];
    __syncthreads();
    int cur = 0;
    const float4v* Mrow = (const float4v*)(M + (size_t)j * S_DIM);
    for (int i = 1; i < GSZ; i++) {
        float acc = F[(((size_t)(g * GSZ + i)) * BBATCH + b) * S_DIM + j];
#pragma unroll 8
        for (int kq = 0; kq < S_DIM / 4; kq++) {
            float4v m = Mrow[kq];
            float4v cv = *(const float4v*)&c[cur][kq * 4];
            acc += m[0]*cv[0] + m[1]*cv[1] + m[2]*cv[2] + m[3]*cv[3];
        }
        c[1 ^ cur][j] = acc;
        __syncthreads();
        cur ^= 1;
    }
    Sg[((size_t)g * BBATCH + b) * S_DIM + j] = c[cur][j];
}

__global__ __launch_bounds__(256) void k_comb_serial(const float* __restrict__ Mg,
                                                     const float* __restrict__ Sg,
                                                     const float* __restrict__ x0,
                                                     float* __restrict__ Gs) {
    const int b = blockIdx.x, j = threadIdx.x;
    __shared__ float c[2][S_DIM];
    float v = x0[(size_t)b * S_DIM + j];
    Gs[(size_t)b * S_DIM + j] = v;  // Gs[g=0]
    c[0][j] = v;
    __syncthreads();
    int cur = 0;
    const float4v* Mrow = (const float4v*)(Mg + (size_t)j * S_DIM);
    for (int g = 1; g < NGRP; g++) {
        float acc = Sg[(((size_t)(g - 1)) * BBATCH + b) * S_DIM + j];
#pragma unroll 8
        for (int kq = 0; kq < S_DIM / 4; kq++) {
            float4v m = Mrow[kq];
            float4v cv = *(const float4v*)&c[cur][kq * 4];
            acc += m[0]*cv[0] + m[1]*cv[1] + m[2]*cv[2] + m[3]*cv[3];
        }
        c[1 ^ cur][j] = acc;
        __syncthreads();
        cur ^= 1;
        Gs[((size_t)g * BBATCH + b) * S_DIM + j] = acc;
    }
}

__global__ __launch_bounds__(256) void k_comb_start(const float* __restrict__ M,
                                                    const float* __restrict__ F,
                                                    const float* __restrict__ Gs,
                                                    float* __restrict__ C) {
    const int g = blockIdx.x, b = blockIdx.y, j = threadIdx.x;
    __shared__ float c[2][S_DIM];
    float v = Gs[((size_t)g * BBATCH + b) * S_DIM + j];
    C[(((size_t)g * GSZ) * BBATCH + b) * S_DIM + j] = v;  // C[p = g*GSZ]
    c[0][j] = v;
    __syncthreads();
    int cur = 0;
    const float4v* Mrow = (const float4v*)(M + (size_t)j * S_DIM);
    for (int i = 1; i < GSZ; i++) {
        float acc = F[(((size_t)(g * GSZ + i - 1)) * BBATCH + b) * S_DIM + j];
#pragma unroll 8
        for (int kq = 0; kq < S_DIM / 4; kq++) {
            float4v m = Mrow[kq];
            float4v cv = *(const float4v*)&c[cur][kq * 4];
            acc += m[0]*cv[0] + m[1]*cv[1] + m[2]*cv[2] + m[3]*cv[3];
        }
        c[1 ^ cur][j] = acc;
        __syncthreads();
        cur ^= 1;
        C[(((size_t)(g * GSZ + i)) * BBATCH + b) * S_DIM + j] = acc;
    }
}

// ---------------------------------------------------------------------------
extern "C" void kernel_launch(void* const* d_in, const int* in_sizes, int n_in,
                              void* d_out, int out_size, void* d_ws, size_t ws_size,
                              hipStream_t stream) {
    const float* x  = (const float*)d_in[0];
    const float* U  = (const float*)d_in[1];
    const float* D  = (const float*)d_in[2];
    const float* Aw = (const float*)d_in[3];
    const float* Bw = (const float*)d_in[4];
    const float* Ew = (const float*)d_in[5];

    float* out  = (float*)d_out;
    float* out1 = out;                                     // X copy 1 (drive scratch)
    float* out2 = out + (size_t)T_STEPS * BBATCH * S_DIM;  // X copy 2 (F scratch first)

    // F lives in out2's first 4 MB: consumed by phase2 before phase3 writes out2.
    float* F = out2;

    // ws layout (floats): C(4MB) | Sg | Gs | M1 M2 M3 | Ah Am Al (bf16)
    float* C   = (float*)d_ws;                              // 64*64*256
    float* Sg  = C  + (size_t)P_CHUNKS * BBATCH * S_DIM;    // 8*64*256
    float* Gs  = Sg + (size_t)NGRP * BBATCH * S_DIM;
    float* M1  = Gs + (size_t)NGRP * BBATCH * S_DIM;
    float* M2  = M1 + (size_t)S_DIM * S_DIM;
    float* M3  = M2 + (size_t)S_DIM * S_DIM;
    short* AhS = (short*)(M3 + (size_t)S_DIM * S_DIM);
    short* AmS = AhS + (size_t)S_DIM * S_DIM;
    short* AlS = AmS + (size_t)S_DIM * S_DIM;

    // 1) drive -> out1   (grid (T,4), 16 b per block)
    k_drive<<<dim3(T_STEPS, 4), 256, 0, stream>>>(U, D, Bw, Ew, out1);

    // 2) A splits for MFMA
    k_splitA<<<64, 256, 0, stream>>>(Aw, AhS, AmS, AlS);

    // 3) matrix powers: M1 = A^32, M2 = A^256
    k_matsq<<<S_DIM, 256, 0, stream>>>(Aw, M1);  // A^2
    k_matsq<<<S_DIM, 256, 0, stream>>>(M1, M2);  // A^4
    k_matsq<<<S_DIM, 256, 0, stream>>>(M2, M1);  // A^8
    k_matsq<<<S_DIM, 256, 0, stream>>>(M1, M2);  // A^16
    k_matsq<<<S_DIM, 256, 0, stream>>>(M2, M1);  // A^32  = M
    k_matsq<<<S_DIM, 256, 0, stream>>>(M1, M2);  // A^64
    k_matsq<<<S_DIM, 256, 0, stream>>>(M2, M3);  // A^128
    k_matsq<<<S_DIM, 256, 0, stream>>>(M3, M2);  // A^256 = Mg

    // 4) phase 1: chunk-local scans from zero -> F
    k_scan<false><<<dim3(P_CHUNKS, BG), 512, 0, stream>>>(AhS, AmS, AlS, out1,
                                                          nullptr, F, nullptr, nullptr);

    // 5) phase 2: two-level chunk combine -> C (chunk start states)
    k_comb_zero<<<dim3(NGRP, BBATCH), 256, 0, stream>>>(M1, F, Sg);
    k_comb_serial<<<BBATCH, 256, 0, stream>>>(M2, Sg, x, Gs);
    k_comb_start<<<dim3(NGRP, BBATCH), 256, 0, stream>>>(M1, F, Gs, C);

    // 6) phase 3: final scans from C, write X to both outputs
    k_scan<true><<<dim3(P_CHUNKS, BG), 512, 0, stream>>>(AhS, AmS, AlS, out1,
                                                         C, nullptr, out1, out2);
}